// Round 3
// baseline (377.382 us; speedup 1.0000x reference)
//
#include <hip/hip_runtime.h>

// Problem constants (reference: B=32, L=1024, DG=1024, H=1024), all float32.
#define BB 32
#define LL 1024
#define DGG 1024
#define HH 1024

// Fully fused: per block = (b, 16 consecutive l rows).
//   gate[l] = sigmoid(query[b,:] . W[:,l] + bias[l])   (16 dots, in-block)
//   out[b,l,0:1024]    = gate[l] * graph[b,l,:]
//   out[b,l,1024:2048] = query[b,:]                    (held in registers)
// grid: (32 b, 128 ltiles) -> 2048 blocks = 8/CU, all co-resident.
// blockIdx.x = b fastest: 32 consecutive blocks share one 64 KB W slice (L2 reuse).
__global__ __launch_bounds__(256) void fused_kernel(
    const float* __restrict__ graph,  // [B,L,DG]
    const float* __restrict__ query,  // [B,H]
    const float* __restrict__ W,      // [H,L]
    const float* __restrict__ bias,   // [L]
    float* __restrict__ out)          // [B,L,DG+H]
{
    __shared__ float qs[HH];          // staged query row (4 KB)
    __shared__ float partial[16][16]; // h-group partial sums per l
    __shared__ float gate_s[16];

    const int b  = blockIdx.x;            // 0..31
    const int l0 = blockIdx.y * 16;       // row tile base
    const int t  = threadIdx.x;

    // Stage query row; each thread also keeps its own quad in registers.
    const float4* q4p = reinterpret_cast<const float4*>(query + (size_t)b * HH);
    float4 q4 = q4p[t];                   // 256 threads x float4 = whole row
    reinterpret_cast<float4*>(qs)[t] = q4;
    __syncthreads();

    // Gate phase: thread (hg = t>>4, j = t&15) accumulates h-range [hg*64, hg*64+64)
    // for column l0+j. Bank-rotate the qs index by hg*4 so the 4 h-groups in a
    // wave hit distinct LDS banks (conflict-free instead of 4-way).
    const int j  = t & 15;
    const int hg = t >> 4;
    const float* Wbase = W + l0 + j;
    float sum = 0.f;
    #pragma unroll 8
    for (int i = 0; i < 64; ++i) {
        const int h = hg * 64 + ((i + hg * 4) & 63);
        sum += qs[h] * Wbase[(size_t)h * LL];
    }
    partial[hg][j] = sum;
    __syncthreads();

    if (t < 16) {
        float s = bias[l0 + t];
        #pragma unroll
        for (int k = 0; k < 16; ++k) s += partial[k][t];
        gate_s[t] = 1.0f / (1.0f + __expf(-s));
    }
    __syncthreads();

    // Stream phase: 16 rows; per row one scaled graph quad + the query quad.
    const float4* g4 = reinterpret_cast<const float4*>(graph) + ((size_t)b * LL + l0) * 256;
    float4*       o4 = reinterpret_cast<float4*>(out)         + ((size_t)b * LL + l0) * 512;
    #pragma unroll 4
    for (int r = 0; r < 16; ++r) {
        const float g = gate_s[r];
        float4 v = g4[(size_t)r * 256 + t];
        float4 sv = make_float4(v.x * g, v.y * g, v.z * g, v.w * g);
        o4[(size_t)r * 512 + t]       = sv;
        o4[(size_t)r * 512 + 256 + t] = q4;
    }
}

extern "C" void kernel_launch(void* const* d_in, const int* in_sizes, int n_in,
                              void* d_out, int out_size, void* d_ws, size_t ws_size,
                              hipStream_t stream) {
    const float* graph = (const float*)d_in[0]; // [B,L,DG]
    const float* query = (const float*)d_in[1]; // [B,H]
    const float* W     = (const float*)d_in[2]; // [H,L]
    const float* bias  = (const float*)d_in[3]; // [L]
    float* out = (float*)d_out;

    dim3 grid(BB, LL / 16);   // x = b fastest -> W-slice reuse across consecutive blocks
    fused_kernel<<<grid, 256, 0, stream>>>(graph, query, W, bias, out);
}